// Round 4
// baseline (317.179 us; speedup 1.0000x reference)
//
#include <hip/hip_runtime.h>
#include <hip/hip_bf16.h>

#define NODES 32768
#define HD 128
#define NE 524288
#define NR 8
#define NS 262144                          // 4 pass-halves * NODES * 2 keys
#define PASSB 65536                        // keys per pass = NODES*2

typedef unsigned int u32;
typedef unsigned short u16;
typedef __attribute__((ext_vector_type(8))) short bf16x8;
typedef __attribute__((ext_vector_type(4))) float f32x4;

// ---- ws byte offsets ----
#define XH_OFF   (0u)                      // bf16 hi x, 8 MB
#define XL_OFF   (8u<<20)                  // bf16 lo x, 8 MB
#define XH2_OFF  (16u<<20)                 // layer-1 x hi
#define XL2_OFF  (24u<<20)                 // layer-1 x lo
#define ADJ_OFF  (32u<<20)                 // u32 x NE packed (src | row<<15)
#define RP_OFF   (34u<<20)                 // u32 x (NS+1)
#define CUR_OFF  (36u<<20)                 // u32 x NS
#define BSUM_OFF (37u<<20)                 // u32 x 1025
#define BP_OFF   (38u<<20)                 // packed weights bf16

#define BP_LAYER 294912                    // 9*2*16384
#define PP_ELEM  589824                    // pW packed at Bp+PP_ELEM

__device__ __forceinline__ float bflo(u32 u){ union{u32 i;float f;}c; c.i=u<<16; return c.f; }
__device__ __forceinline__ float bfhi(u32 u){ union{u32 i;float f;}c; c.i=u&0xffff0000u; return c.f; }
__device__ __forceinline__ u16 f2bf(float f){
  u32 u=__float_as_uint(f);
  u32 r=u + 0x7fffu + ((u>>16)&1u);
  return (u16)(r>>16);
}
__device__ __forceinline__ float bf2f(u16 h){ return __uint_as_float(((u32)h)<<16); }

__device__ __forceinline__ void gl_lds16(const void* g, void* l){
  __builtin_amdgcn_global_load_lds((const __attribute__((address_space(1))) u32*)g,
                                   (__attribute__((address_space(3))) u32*)l, 16, 0, 0);
}

// ---------------- weight prep: 2 layers x 9 tiles (8 rel + self) + pW, hi/lo segs ----
__global__ void prep_w(const float* __restrict__ rW, const float* __restrict__ sW,
                       const float* __restrict__ pWg, u16* __restrict__ Bp)
{
  int idx=blockIdx.x*256+threadIdx.x;           // 311296 total
  if(idx<294912){
    int l=idx/147456;
    int rem=idx%147456;
    int t=rem>>14;
    int kn=rem&16383;
    int k=kn>>7, n=kn&127;
    float w;
    if(t<8) w=rW[(((size_t)l*NR+t)*HD+n)*HD+k];
    else    w=sW[((size_t)l*HD+n)*HD+k];
    u16* base=Bp+(size_t)l*BP_LAYER+(size_t)t*32768;
    int ks=k>>5, q=(k>>3)&3, j=k&7;
    size_t off=((size_t)ks*128+n)*32+q*8+j;
    u16 hb=f2bf(w);
    u16 lb=f2bf(w-bf2f(hb));
    base[off]=hb;
    base[off+16384]=lb;
  } else {
    int kn=idx-294912;
    int k=kn>>7, n=kn&127;
    float w=pWg[(size_t)n*HD+k];
    u16* base=Bp+PP_ELEM;
    int ks=k>>5, q=(k>>3)&3, j=k&7;
    size_t off=((size_t)ks*128+n)*32+q*8+j;
    u16 hb=f2bf(w);
    u16 lb=f2bf(w-bf2f(hb));
    base[off]=hb;
    base[off+16384]=lb;
  }
}

// ---------------- embed_mfma: x = (cemb[cid]+kemb[kid]) @ pW^T + pb -> xh/xl ----------
__global__ __launch_bounds__(256,2) void embed_mfma(
    const int* __restrict__ cid, const int* __restrict__ kid,
    const float* __restrict__ cemb, const float* __restrict__ kemb,
    const u16* __restrict__ PP, const float* __restrict__ pb,
    u16* __restrict__ xh, u16* __restrict__ xl)
{
  __shared__ u16 Atile[2][128*128];   // [0]=hi [1]=lo, 64 KB, XOR-16 swizzle
  const int tid=threadIdx.x;
  const int wave=tid>>6, lane=tid&63;
  const int wm=wave>>1, wn=wave&1;
  const int q=lane>>4;
  const int d0=blockIdx.x*128;

  { int r=tid>>1, half=tid&1;
    int ci=cid[d0+r], ki=kid[d0+r];
    const float* cp=cemb+(size_t)ci*HD+half*64;
    const float* kp=kemb+(size_t)ki*HD+half*64;
#pragma unroll
    for(int cc=0;cc<8;cc++){
      float4 a0=*(const float4*)(cp+cc*8);
      float4 a1=*(const float4*)(cp+cc*8+4);
      float4 b0=*(const float4*)(kp+cc*8);
      float4 b1=*(const float4*)(kp+cc*8+4);
      float v[8]={a0.x+b0.x,a0.y+b0.y,a0.z+b0.z,a0.w+b0.w,
                  a1.x+b1.x,a1.y+b1.y,a1.z+b1.z,a1.w+b1.w};
      u16 hb[8], lb[8];
#pragma unroll
      for(int j=0;j<8;j++){ hb[j]=f2bf(v[j]); lb[j]=f2bf(v[j]-bf2f(hb[j])); }
      int chunk=half*8+cc;
      int dst=r*128+(chunk^(r&15))*8;
      uint4 hv={(u32)hb[0]|((u32)hb[1]<<16),(u32)hb[2]|((u32)hb[3]<<16),
                (u32)hb[4]|((u32)hb[5]<<16),(u32)hb[6]|((u32)hb[7]<<16)};
      uint4 lv={(u32)lb[0]|((u32)lb[1]<<16),(u32)lb[2]|((u32)lb[3]<<16),
                (u32)lb[4]|((u32)lb[5]<<16),(u32)lb[6]|((u32)lb[7]<<16)};
      *(uint4*)&Atile[0][dst]=hv;
      *(uint4*)&Atile[1][dst]=lv;
    }
  }
  __syncthreads();

  f32x4 acc[4][4];
#pragma unroll
  for(int a=0;a<4;a++)
#pragma unroll
    for(int b=0;b<4;b++) acc[a][b]=(f32x4){0.f,0.f,0.f,0.f};

#pragma unroll
  for(int ks=0;ks<4;ks++){
    bf16x8 ah[4];
#pragma unroll
    for(int tm=0;tm<4;tm++){
      int m=wm*64+tm*16+(lane&15);
      ah[tm]=*(const bf16x8*)&Atile[0][m*128+(((ks*4)+q)^(m&15))*8];
    }
#pragma unroll
    for(int s=0;s<2;s++){
      const u16* Bb=PP+s*16384;
#pragma unroll
      for(int tn=0;tn<4;tn++){
        int n=wn*64+tn*16+(lane&15);
        bf16x8 bfr=*(const bf16x8*)&Bb[((size_t)ks*128+n)*32+q*8];
#pragma unroll
        for(int tm=0;tm<4;tm++)
          acc[tm][tn]=__builtin_amdgcn_mfma_f32_16x16x32_bf16(ah[tm],bfr,acc[tm][tn],0,0,0);
      }
    }
  }
#pragma unroll
  for(int ks=0;ks<4;ks++){
    bf16x8 al[4];
#pragma unroll
    for(int tm=0;tm<4;tm++){
      int m=wm*64+tm*16+(lane&15);
      al[tm]=*(const bf16x8*)&Atile[1][m*128+(((ks*4)+q)^(m&15))*8];
    }
#pragma unroll
    for(int tn=0;tn<4;tn++){
      int n=wn*64+tn*16+(lane&15);
      bf16x8 bfr=*(const bf16x8*)&PP[((size_t)ks*128+n)*32+q*8];
#pragma unroll
      for(int tm=0;tm<4;tm++)
        acc[tm][tn]=__builtin_amdgcn_mfma_f32_16x16x32_bf16(al[tm],bfr,acc[tm][tn],0,0,0);
    }
  }

#pragma unroll
  for(int tn=0;tn<4;tn++){
    int n=wn*64+tn*16+(lane&15);
    float b=pb[n];
#pragma unroll
    for(int tm=0;tm<4;tm++){
      int rbase=d0+wm*64+tm*16+q*4;
#pragma unroll
      for(int r=0;r<4;r++){
        float v=acc[tm][tn][r]+b;
        u16 hb=f2bf(v);
        u16 lb=f2bf(v-bf2f(hb));
        xh[(size_t)(rbase+r)*HD+n]=hb;
        xl[(size_t)(rbase+r)*HD+n]=lb;
      }
    }
  }
}

// ---------------- CSR build, key = (et>>1)*PASSB + dst*2 + (et&1) ----------------
__global__ void count_deg2(const int* __restrict__ dst, const int* __restrict__ et,
                           u32* __restrict__ cnt){
  int e=blockIdx.x*256+threadIdx.x;
  int t=et[e];
  int key=(t>>1)*PASSB + dst[e]*2 + (t&1);
  atomicAdd(&cnt[key],1u);
}

__global__ void scan1(u32* __restrict__ cnt, u32* __restrict__ rp, u32* __restrict__ bsum){
  __shared__ u32 sh[256];
  int t=threadIdx.x; int base=blockIdx.x*256;
  u32 v=cnt[base+t]; sh[t]=v;
  cnt[base+t]=0u;                       // re-zero cur for scatter
  __syncthreads();
  for(int off=1;off<256;off<<=1){
    u32 tv=(t>=off)?sh[t-off]:0u; __syncthreads();
    sh[t]+=tv; __syncthreads();
  }
  rp[base+t]=sh[t]-v;
  if(t==255) bsum[blockIdx.x]=sh[255];
}

__global__ void scan2b(u32* __restrict__ bsum, u32* __restrict__ rp){
  __shared__ u32 sh[256];
  int t=threadIdx.x;
  u32 v0=bsum[t*4+0],v1=bsum[t*4+1],v2=bsum[t*4+2],v3=bsum[t*4+3];
  u32 s=v0+v1+v2+v3;
  sh[t]=s; __syncthreads();
  for(int off=1;off<256;off<<=1){
    u32 tv=(t>=off)?sh[t-off]:0u; __syncthreads();
    sh[t]+=tv; __syncthreads();
  }
  u32 ex=sh[t]-s;
  bsum[t*4+0]=ex; bsum[t*4+1]=ex+v0; bsum[t*4+2]=ex+v0+v1; bsum[t*4+3]=ex+v0+v1+v2;
  if(t==0) rp[NS]=NE;
  if(t==255) bsum[1024]=0u;
}

__global__ void scatter_edges2(const int* __restrict__ src, const int* __restrict__ dst,
                               const int* __restrict__ et, const u32* __restrict__ rp,
                               const u32* __restrict__ bsum,
                               u32* __restrict__ cur, u32* __restrict__ adj){
  int e=blockIdx.x*256+threadIdx.x;
  int t=et[e];
  int d=dst[e];
  int key=(t>>1)*PASSB + d*2 + (t&1);
  u32 pos=atomicAdd(&cur[key],1u);
  u32 val=(u32)src[e] | (((u32)(((t&1)<<5)|(d&31)))<<15);   // src | localrow<<15
  adj[rp[key]+bsum[key>>8]+pos]=val;
}

// ---------------- fused_layer ----------------
// Per 32-dst block: 4 passes x { gather-sum x[src] rows per (d,rl) segment (register
// accum, exclusive row ownership, hi/lo split flush into LDS) -> GEMM 2 relations },
// then self-GEMM from LDS-staged x, then /deg + bias + relu + hi/lo split out.
// No y, no z, no second kernel. LDS 32 KB -> 4 blocks/CU.
#define FLUSHROW(rw,a0,a1) do{ \
  u16 fh0=f2bf(a0), fh1=f2bf(a1); \
  u16 fl0=f2bf((a0)-bf2f(fh0)), fl1=f2bf((a1)-bf2f(fh1)); \
  int fw=(rw)*64 + (((lane>>2)^((rw)&15))<<2) + (lane&3); \
  ((u32*)As[0])[fw]=(u32)fh0|((u32)fh1<<16); \
  ((u32*)As[1])[fw]=(u32)fl0|((u32)fl1<<16); \
}while(0)

__global__ __launch_bounds__(256,4) void fused_layer(
    const u16* __restrict__ xh, const u16* __restrict__ xl,
    const u16* __restrict__ Bp,
    const u32* __restrict__ rp, const u32* __restrict__ bsum,
    const u32* __restrict__ adj,
    const float* __restrict__ sb, const int* __restrict__ mask,
    u16* __restrict__ oh, u16* __restrict__ ol, float* __restrict__ outf, int last)
{
  __shared__ u16 As[2][64*128];     // 32 KB: [0]=hi [1]=lo; XOR-16 swizzled rows
  __shared__ float sdeg[32];
  const int tid=threadIdx.x;
  const int wave=tid>>6, lane=tid&63;
  const int q=lane>>4;
  const int d0=blockIdx.x*32;
  const u32* xh32=(const u32*)xh;
  const u32* xl32=(const u32*)xl;

  f32x4 accR[2][2], accS[2][2];
#pragma unroll
  for(int a=0;a<2;a++)
#pragma unroll
    for(int b=0;b<2;b++){ accR[a][b]=(f32x4){0.f,0.f,0.f,0.f}; accS[a][b]=(f32x4){0.f,0.f,0.f,0.f}; }

  for(int p=0;p<4;p++){
    // zero owned rows (wave owns d in [wave*8,wave*8+8), rl 0..1 -> 16 rows)
    { uint4 zz={0u,0u,0u,0u};
#pragma unroll
      for(int rl=0;rl<2;rl++)
#pragma unroll
        for(int i=0;i<2;i++){
          int row=rl*32+wave*8+i*4+(lane>>4);
          int col16=lane&15;
          *(uint4*)&As[0][row*128+col16*8]=zz;
          *(uint4*)&As[1][row*128+col16*8]=zz;
        }
    }
    // gather: wave's contiguous key range (8 dsts x 2 rels)
    { u32 k0=(u32)(p*PASSB + (d0+wave*8)*2);
      u32 begW=rp[k0]+bsum[k0>>8];
      u32 k1=k0+16;
      u32 endW=rp[k1]+bsum[k1>>8];
      int currow=-1; float v0=0.f,v1=0.f;
      for(u32 base=begW; base<endW; base+=64){
        int nk=(int)(endW-base); if(nk>64) nk=64;
        u32 adjv=(lane<nk)?adj[base+lane]:0u;
        int i=0;
        for(; i+4<=nk; i+=4){
          u32 w0=(u32)__shfl((int)adjv,i+0);
          u32 w1=(u32)__shfl((int)adjv,i+1);
          u32 w2=(u32)__shfl((int)adjv,i+2);
          u32 w3=(u32)__shfl((int)adjv,i+3);
          u32 h0=xh32[(size_t)(w0&0x7fffu)*64+lane], l0=xl32[(size_t)(w0&0x7fffu)*64+lane];
          u32 h1=xh32[(size_t)(w1&0x7fffu)*64+lane], l1=xl32[(size_t)(w1&0x7fffu)*64+lane];
          u32 h2=xh32[(size_t)(w2&0x7fffu)*64+lane], l2=xl32[(size_t)(w2&0x7fffu)*64+lane];
          u32 h3=xh32[(size_t)(w3&0x7fffu)*64+lane], l3=xl32[(size_t)(w3&0x7fffu)*64+lane];
          int r0=(int)(w0>>15);
          if(r0!=currow){ if(currow>=0) FLUSHROW(currow,v0,v1); currow=r0; v0=0.f; v1=0.f; }
          v0+=bflo(h0)+bflo(l0); v1+=bfhi(h0)+bfhi(l0);
          int r1=(int)(w1>>15);
          if(r1!=currow){ FLUSHROW(currow,v0,v1); currow=r1; v0=0.f; v1=0.f; }
          v0+=bflo(h1)+bflo(l1); v1+=bfhi(h1)+bfhi(l1);
          int r2=(int)(w2>>15);
          if(r2!=currow){ FLUSHROW(currow,v0,v1); currow=r2; v0=0.f; v1=0.f; }
          v0+=bflo(h2)+bflo(l2); v1+=bfhi(h2)+bfhi(l2);
          int r3=(int)(w3>>15);
          if(r3!=currow){ FLUSHROW(currow,v0,v1); currow=r3; v0=0.f; v1=0.f; }
          v0+=bflo(h3)+bflo(l3); v1+=bfhi(h3)+bfhi(l3);
        }
        for(; i<nk; i++){
          u32 w0=(u32)__shfl((int)adjv,i);
          u32 h=xh32[(size_t)(w0&0x7fffu)*64+lane], l=xl32[(size_t)(w0&0x7fffu)*64+lane];
          int r0=(int)(w0>>15);
          if(r0!=currow){ if(currow>=0) FLUSHROW(currow,v0,v1); currow=r0; v0=0.f; v1=0.f; }
          v0+=bflo(h)+bflo(l); v1+=bfhi(h)+bfhi(l);
        }
      }
      if(currow>=0) FLUSHROW(currow,v0,v1);
    }
    __syncthreads();
    // GEMM relations 2p, 2p+1
#pragma unroll
    for(int rl=0;rl<2;rl++){
      const u16* Bt=Bp+(size_t)(p*2+rl)*32768;
#pragma unroll
      for(int ks=0;ks<4;ks++){
        bf16x8 ah[2],al[2];
#pragma unroll
        for(int mf=0;mf<2;mf++){
          int ar=rl*32+mf*16+(lane&15);
          int off=ar*128+((((ks<<2)+q)^(ar&15))<<3);
          ah[mf]=*(const bf16x8*)&As[0][off];
          al[mf]=*(const bf16x8*)&As[1][off];
        }
#pragma unroll
        for(int tn=0;tn<2;tn++){
          int n=wave*32+tn*16+(lane&15);
          size_t boff=((size_t)(ks*128+n))*32+q*8;
          bf16x8 bh=*(const bf16x8*)&Bt[boff];
          bf16x8 bl=*(const bf16x8*)&Bt[boff+16384];
#pragma unroll
          for(int mf=0;mf<2;mf++){
            accR[mf][tn]=__builtin_amdgcn_mfma_f32_16x16x32_bf16(ah[mf],bh,accR[mf][tn],0,0,0);
            accR[mf][tn]=__builtin_amdgcn_mfma_f32_16x16x32_bf16(al[mf],bh,accR[mf][tn],0,0,0);
            accR[mf][tn]=__builtin_amdgcn_mfma_f32_16x16x32_bf16(ah[mf],bl,accR[mf][tn],0,0,0);
          }
        }
      }
    }
    __syncthreads();
  }

  // ---- self: stage x rows d0..d0+31 hi/lo into As rows 0..31, deg into LDS ----
#pragma unroll
  for(int i=0;i<2;i++){
    int rbase=wave*8+i*4;
    int r=rbase+(lane>>4);
    int g=(lane&15)^(r&15);
    gl_lds16(xh+(size_t)(d0+r)*HD+g*8, &As[0][rbase*128]);
  }
#pragma unroll
  for(int i=0;i<2;i++){
    int rbase=wave*8+i*4;
    int r=rbase+(lane>>4);
    int g=(lane&15)^(r&15);
    gl_lds16(xl+(size_t)(d0+r)*HD+g*8, &As[1][rbase*128]);
  }
  if(tid<32){
    int g=d0+tid; u32 dg=0;
#pragma unroll
    for(int ph=0;ph<4;ph++){
      u32 k=(u32)(ph*PASSB+g*2);
      dg+=(rp[k+2]+bsum[(k+2)>>8])-(rp[k]+bsum[k>>8]);
    }
    sdeg[tid]=1.f/fmaxf((float)dg,1.f);
  }
  __syncthreads();
  { const u16* Bt=Bp+(size_t)8*32768;
#pragma unroll
    for(int ks=0;ks<4;ks++){
      bf16x8 ah[2],al[2];
#pragma unroll
      for(int mf=0;mf<2;mf++){
        int ar=mf*16+(lane&15);
        int off=ar*128+((((ks<<2)+q)^(ar&15))<<3);
        ah[mf]=*(const bf16x8*)&As[0][off];
        al[mf]=*(const bf16x8*)&As[1][off];
      }
#pragma unroll
      for(int tn=0;tn<2;tn++){
        int n=wave*32+tn*16+(lane&15);
        size_t boff=((size_t)(ks*128+n))*32+q*8;
        bf16x8 bh=*(const bf16x8*)&Bt[boff];
        bf16x8 bl=*(const bf16x8*)&Bt[boff+16384];
#pragma unroll
        for(int mf=0;mf<2;mf++){
          accS[mf][tn]=__builtin_amdgcn_mfma_f32_16x16x32_bf16(ah[mf],bh,accS[mf][tn],0,0,0);
          accS[mf][tn]=__builtin_amdgcn_mfma_f32_16x16x32_bf16(al[mf],bh,accS[mf][tn],0,0,0);
          accS[mf][tn]=__builtin_amdgcn_mfma_f32_16x16x32_bf16(ah[mf],bl,accS[mf][tn],0,0,0);
        }
      }
    }
  }

  // ---- epilogue: out = relu(accS + sb + accR/deg); C/D: col=lane&15, row=q*4+reg ----
#pragma unroll
  for(int tn=0;tn<2;tn++){
    int n=wave*32+tn*16+(lane&15);
    float bb=sb[n];
    if(last){
#pragma unroll
      for(int mf=0;mf<2;mf++)
#pragma unroll
        for(int rr=0;rr<4;rr++){
          int row=mf*16+q*4+rr;
          float v=fmaxf(accS[mf][tn][rr]+bb+accR[mf][tn][rr]*sdeg[row],0.f);
          v*=(float)mask[d0+row];
          outf[(size_t)(d0+row)*HD+n]=v;
        }
    } else {
#pragma unroll
      for(int mf=0;mf<2;mf++)
#pragma unroll
        for(int rr=0;rr<4;rr++){
          int row=mf*16+q*4+rr;
          float v=fmaxf(accS[mf][tn][rr]+bb+accR[mf][tn][rr]*sdeg[row],0.f);
          u16 hb=f2bf(v);
          u16 lb=f2bf(v-bf2f(hb));
          oh[(size_t)(d0+row)*HD+n]=hb;
          ol[(size_t)(d0+row)*HD+n]=lb;
        }
    }
  }
}

extern "C" void kernel_launch(void* const* d_in, const int* in_sizes, int n_in,
                              void* d_out, int out_size, void* d_ws, size_t ws_size,
                              hipStream_t stream)
{
  (void)in_sizes; (void)n_in; (void)out_size; (void)ws_size;
  const int*   cid =(const int*)  d_in[0];
  const int*   kid =(const int*)  d_in[1];
  const int*   mask=(const int*)  d_in[2];
  const int*   ei  =(const int*)  d_in[3];
  const int*   et  =(const int*)  d_in[4];
  const float* cemb=(const float*)d_in[5];
  const float* kemb=(const float*)d_in[6];
  const float* pW  =(const float*)d_in[7];
  const float* pb  =(const float*)d_in[8];
  const float* sW  =(const float*)d_in[9];
  const float* sb  =(const float*)d_in[10];
  const float* rW  =(const float*)d_in[11];
  float* out=(float*)d_out;
  char*  ws =(char*)d_ws;

  u16* xh =(u16*)(ws+XH_OFF);
  u16* xl =(u16*)(ws+XL_OFF);
  u16* xh2=(u16*)(ws+XH2_OFF);
  u16* xl2=(u16*)(ws+XL2_OFF);
  u32* adj =(u32*)(ws+ADJ_OFF);
  u32* rp  =(u32*)(ws+RP_OFF);
  u32* cur =(u32*)(ws+CUR_OFF);
  u32* bsum=(u32*)(ws+BSUM_OFF);
  u16* Bp  =(u16*)(ws+BP_OFF);
  const int* srcA=ei;
  const int* dstA=ei+NE;

  hipMemsetAsync(cur,0,NS*sizeof(u32),stream);
  prep_w<<<1216,256,0,stream>>>(rW,sW,pW,Bp);
  embed_mfma<<<NODES/128,256,0,stream>>>(cid,kid,cemb,kemb,Bp+PP_ELEM,pb,xh,xl);
  count_deg2<<<NE/256,256,0,stream>>>(dstA,et,cur);
  scan1<<<NS/256,256,0,stream>>>(cur,rp,bsum);
  scan2b<<<1,256,0,stream>>>(bsum,rp);
  scatter_edges2<<<NE/256,256,0,stream>>>(srcA,dstA,et,rp,bsum,cur,adj);

  fused_layer<<<NODES/32,256,0,stream>>>(xh,xl,Bp,rp,bsum,adj,sb,mask,xh2,xl2,out,0);
  fused_layer<<<NODES/32,256,0,stream>>>(xh2,xl2,Bp+BP_LAYER,rp,bsum,adj,sb+HD,mask,xh,xl,out,1);
}

// Round 5
// 301.173 us; speedup vs baseline: 1.0531x; 1.0531x over previous
//
#include <hip/hip_runtime.h>
#include <hip/hip_bf16.h>

#define NODES 32768
#define HD 128
#define NE 524288
#define NR 8
#define NS 262144                          // 4 pass-halves * NODES * 2 keys
#define PASSB 65536                        // keys per pass = NODES*2

typedef unsigned int u32;
typedef unsigned short u16;
typedef __attribute__((ext_vector_type(8))) short bf16x8;
typedef __attribute__((ext_vector_type(4))) float f32x4;

// ---- ws byte offsets ----
#define XH_OFF   (0u)                      // bf16 hi x, 8 MB
#define XL_OFF   (8u<<20)                  // bf16 lo x, 8 MB
#define XH2_OFF  (16u<<20)                 // layer-1 x hi
#define XL2_OFF  (24u<<20)                 // layer-1 x lo
#define ADJ_OFF  (32u<<20)                 // u32 x NE packed (src | row<<15)
#define RP_OFF   (34u<<20)                 // u32 x (NS+1)
#define CUR_OFF  (36u<<20)                 // u32 x NS
#define BSUM_OFF (37u<<20)                 // u32 x 1025
#define BP_OFF   (38u<<20)                 // packed weights bf16

#define BP_LAYER 294912                    // 9*2*16384
#define PP_ELEM  589824                    // pW packed at Bp+PP_ELEM

__device__ __forceinline__ float bflo(u32 u){ union{u32 i;float f;}c; c.i=u<<16; return c.f; }
__device__ __forceinline__ float bfhi(u32 u){ union{u32 i;float f;}c; c.i=u&0xffff0000u; return c.f; }
__device__ __forceinline__ u16 f2bf(float f){
  u32 u=__float_as_uint(f);
  u32 r=u + 0x7fffu + ((u>>16)&1u);
  return (u16)(r>>16);
}
__device__ __forceinline__ float bf2f(u16 h){ return __uint_as_float(((u32)h)<<16); }

__device__ __forceinline__ void gl_lds16(const void* g, void* l){
  __builtin_amdgcn_global_load_lds((const __attribute__((address_space(1))) u32*)g,
                                   (__attribute__((address_space(3))) u32*)l, 16, 0, 0);
}

// ---------------- weight prep: 2 layers x 9 tiles (8 rel + self) + pW, hi/lo segs ----
__global__ void prep_w(const float* __restrict__ rW, const float* __restrict__ sW,
                       const float* __restrict__ pWg, u16* __restrict__ Bp)
{
  int idx=blockIdx.x*256+threadIdx.x;           // 311296 total
  if(idx<294912){
    int l=idx/147456;
    int rem=idx%147456;
    int t=rem>>14;
    int kn=rem&16383;
    int k=kn>>7, n=kn&127;
    float w;
    if(t<8) w=rW[(((size_t)l*NR+t)*HD+n)*HD+k];
    else    w=sW[((size_t)l*HD+n)*HD+k];
    u16* base=Bp+(size_t)l*BP_LAYER+(size_t)t*32768;
    int ks=k>>5, q=(k>>3)&3, j=k&7;
    size_t off=((size_t)ks*128+n)*32+q*8+j;
    u16 hb=f2bf(w);
    u16 lb=f2bf(w-bf2f(hb));
    base[off]=hb;
    base[off+16384]=lb;
  } else {
    int kn=idx-294912;
    int k=kn>>7, n=kn&127;
    float w=pWg[(size_t)n*HD+k];
    u16* base=Bp+PP_ELEM;
    int ks=k>>5, q=(k>>3)&3, j=k&7;
    size_t off=((size_t)ks*128+n)*32+q*8+j;
    u16 hb=f2bf(w);
    u16 lb=f2bf(w-bf2f(hb));
    base[off]=hb;
    base[off+16384]=lb;
  }
}

// ---------------- embed_mfma: x = (cemb[cid]+kemb[kid]) @ pW^T + pb -> xh/xl ----------
// epilogue now repacks through dead Atile -> linear dwordx4 stores
__global__ __launch_bounds__(256,2) void embed_mfma(
    const int* __restrict__ cid, const int* __restrict__ kid,
    const float* __restrict__ cemb, const float* __restrict__ kemb,
    const u16* __restrict__ PP, const float* __restrict__ pb,
    u16* __restrict__ xh, u16* __restrict__ xl)
{
  __shared__ u16 Atile[2][128*128];   // [0]=hi [1]=lo, 64 KB, XOR-16 swizzle
  const int tid=threadIdx.x;
  const int wave=tid>>6, lane=tid&63;
  const int wm=wave>>1, wn=wave&1;
  const int q=lane>>4;
  const int d0=blockIdx.x*128;

  { int r=tid>>1, half=tid&1;
    int ci=cid[d0+r], ki=kid[d0+r];
    const float* cp=cemb+(size_t)ci*HD+half*64;
    const float* kp=kemb+(size_t)ki*HD+half*64;
#pragma unroll
    for(int cc=0;cc<8;cc++){
      float4 a0=*(const float4*)(cp+cc*8);
      float4 a1=*(const float4*)(cp+cc*8+4);
      float4 b0=*(const float4*)(kp+cc*8);
      float4 b1=*(const float4*)(kp+cc*8+4);
      float v[8]={a0.x+b0.x,a0.y+b0.y,a0.z+b0.z,a0.w+b0.w,
                  a1.x+b1.x,a1.y+b1.y,a1.z+b1.z,a1.w+b1.w};
      u16 hb[8], lb[8];
#pragma unroll
      for(int j=0;j<8;j++){ hb[j]=f2bf(v[j]); lb[j]=f2bf(v[j]-bf2f(hb[j])); }
      int chunk=half*8+cc;
      int dst=r*128+(chunk^(r&15))*8;
      uint4 hv={(u32)hb[0]|((u32)hb[1]<<16),(u32)hb[2]|((u32)hb[3]<<16),
                (u32)hb[4]|((u32)hb[5]<<16),(u32)hb[6]|((u32)hb[7]<<16)};
      uint4 lv={(u32)lb[0]|((u32)lb[1]<<16),(u32)lb[2]|((u32)lb[3]<<16),
                (u32)lb[4]|((u32)lb[5]<<16),(u32)lb[6]|((u32)lb[7]<<16)};
      *(uint4*)&Atile[0][dst]=hv;
      *(uint4*)&Atile[1][dst]=lv;
    }
  }
  __syncthreads();

  f32x4 acc[4][4];
#pragma unroll
  for(int a=0;a<4;a++)
#pragma unroll
    for(int b=0;b<4;b++) acc[a][b]=(f32x4){0.f,0.f,0.f,0.f};

#pragma unroll
  for(int ks=0;ks<4;ks++){
    bf16x8 ah[4];
#pragma unroll
    for(int tm=0;tm<4;tm++){
      int m=wm*64+tm*16+(lane&15);
      ah[tm]=*(const bf16x8*)&Atile[0][m*128+(((ks*4)+q)^(m&15))*8];
    }
#pragma unroll
    for(int s=0;s<2;s++){
      const u16* Bb=PP+s*16384;
#pragma unroll
      for(int tn=0;tn<4;tn++){
        int n=wn*64+tn*16+(lane&15);
        bf16x8 bfr=*(const bf16x8*)&Bb[((size_t)ks*128+n)*32+q*8];
#pragma unroll
        for(int tm=0;tm<4;tm++)
          acc[tm][tn]=__builtin_amdgcn_mfma_f32_16x16x32_bf16(ah[tm],bfr,acc[tm][tn],0,0,0);
      }
    }
  }
#pragma unroll
  for(int ks=0;ks<4;ks++){
    bf16x8 al[4];
#pragma unroll
    for(int tm=0;tm<4;tm++){
      int m=wm*64+tm*16+(lane&15);
      al[tm]=*(const bf16x8*)&Atile[1][m*128+(((ks*4)+q)^(m&15))*8];
    }
#pragma unroll
    for(int tn=0;tn<4;tn++){
      int n=wn*64+tn*16+(lane&15);
      bf16x8 bfr=*(const bf16x8*)&PP[((size_t)ks*128+n)*32+q*8];
#pragma unroll
      for(int tm=0;tm<4;tm++)
        acc[tm][tn]=__builtin_amdgcn_mfma_f32_16x16x32_bf16(al[tm],bfr,acc[tm][tn],0,0,0);
    }
  }

  // ---- epilogue: +pb, hi/lo split into dead Atile (swz bits5-6), linear dwordx4 out ----
  __syncthreads();
  { u16* Sh=(u16*)Atile[0];
    u16* Sl=(u16*)Atile[1];
#pragma unroll
    for(int tn=0;tn<4;tn++){
      int n=wn*64+tn*16+(lane&15);
      float b=pb[n];
#pragma unroll
      for(int tm=0;tm<4;tm++){
        int rbase=wm*64+tm*16+q*4;
#pragma unroll
        for(int r=0;r<4;r++){
          float v=acc[tm][tn][r]+b;
          u16 hb=f2bf(v);
          u16 lb=f2bf(v-bf2f(hb));
          int row=rbase+r;
          u32 ab=(u32)(row*256+n*2);
          ab^=((u32)((row>>2)&3))<<5;
          Sh[ab>>1]=hb;
          Sl[ab>>1]=lb;
        }
      }
    }
  }
  __syncthreads();
  { const char* S0=(const char*)Atile[0];
    const char* S1=(const char*)Atile[1];
    char* xhb=(char*)(xh+(size_t)d0*HD);
    char* xlb=(char*)(xl+(size_t)d0*HD);
#pragma unroll
    for(int i=0;i<8;i++){
      u32 byte=(u32)(i*256+tid)*16;       // 32 KB tile, 16 lanes = one 256B row
      u32 row=byte>>8;
      u32 lb2=byte^((((row>>2)&3))<<5);
      *(uint4*)(xhb+byte)=*(const uint4*)(S0+lb2);
      *(uint4*)(xlb+byte)=*(const uint4*)(S1+lb2);
    }
  }
}

// ---------------- CSR build, key = (et>>1)*PASSB + dst*2 + (et&1) ----------------
__global__ void count_deg2(const int* __restrict__ dst, const int* __restrict__ et,
                           u32* __restrict__ cnt){
  int e=blockIdx.x*256+threadIdx.x;
  int t=et[e];
  int key=(t>>1)*PASSB + dst[e]*2 + (t&1);
  atomicAdd(&cnt[key],1u);
}

__global__ void scan1(u32* __restrict__ cnt, u32* __restrict__ rp, u32* __restrict__ bsum){
  __shared__ u32 sh[256];
  int t=threadIdx.x; int base=blockIdx.x*256;
  u32 v=cnt[base+t]; sh[t]=v;
  cnt[base+t]=0u;                       // re-zero cur for scatter
  __syncthreads();
  for(int off=1;off<256;off<<=1){
    u32 tv=(t>=off)?sh[t-off]:0u; __syncthreads();
    sh[t]+=tv; __syncthreads();
  }
  rp[base+t]=sh[t]-v;
  if(t==255) bsum[blockIdx.x]=sh[255];
}

__global__ void scan2b(u32* __restrict__ bsum, u32* __restrict__ rp){
  __shared__ u32 sh[256];
  int t=threadIdx.x;
  u32 v0=bsum[t*4+0],v1=bsum[t*4+1],v2=bsum[t*4+2],v3=bsum[t*4+3];
  u32 s=v0+v1+v2+v3;
  sh[t]=s; __syncthreads();
  for(int off=1;off<256;off<<=1){
    u32 tv=(t>=off)?sh[t-off]:0u; __syncthreads();
    sh[t]+=tv; __syncthreads();
  }
  u32 ex=sh[t]-s;
  bsum[t*4+0]=ex; bsum[t*4+1]=ex+v0; bsum[t*4+2]=ex+v0+v1; bsum[t*4+3]=ex+v0+v1+v2;
  if(t==0) rp[NS]=NE;
  if(t==255) bsum[1024]=0u;
}

__global__ void scatter_edges2(const int* __restrict__ src, const int* __restrict__ dst,
                               const int* __restrict__ et, const u32* __restrict__ rp,
                               const u32* __restrict__ bsum,
                               u32* __restrict__ cur, u32* __restrict__ adj){
  int e=blockIdx.x*256+threadIdx.x;
  int t=et[e];
  int d=dst[e];
  int key=(t>>1)*PASSB + d*2 + (t&1);
  u32 pos=atomicAdd(&cur[key],1u);
  u32 val=(u32)src[e] | (((u32)(((t&1)<<5)|(d&31)))<<15);   // src | localrow<<15
  adj[rp[key]+bsum[key>>8]+pos]=val;
}

// ---------------- fused_layer ----------------
// Gather: hi-only x reads, scalar (readlane/SALU) edge decode + addressing,
// 8-deep load pipelining, truncation-split flush. Then per-pass GEMM of 2 relations,
// self-GEMM, fused /deg + bias + relu + hi/lo out. LDS 32 KB -> 4 blocks/CU.
#define FLUSH2(rw) do{ \
  u32 u0=__float_as_uint(v0), u1=__float_as_uint(v1); \
  u32 t0=u0&0xffff0000u, t1=u1&0xffff0000u; \
  u32 hp=t1|(u0>>16); \
  float l0f=v0-__uint_as_float(t0), l1f=v1-__uint_as_float(t1); \
  u32 w0b=__float_as_uint(l0f), w1b=__float_as_uint(l1f); \
  u32 lp=(w1b&0xffff0000u)|(w0b>>16); \
  int fw=(rw)*64 + (((lane>>2)^((rw)&15))<<2) + (lane&3); \
  ((u32*)As[0])[fw]=hp; \
  ((u32*)As[1])[fw]=lp; \
}while(0)

__global__ __launch_bounds__(256,4) void fused_layer(
    const u16* __restrict__ xh, const u16* __restrict__ xl,
    const u16* __restrict__ Bp,
    const u32* __restrict__ rp, const u32* __restrict__ bsum,
    const u32* __restrict__ adj,
    const float* __restrict__ sb, const int* __restrict__ mask,
    u16* __restrict__ oh, u16* __restrict__ ol, float* __restrict__ outf, int last)
{
  __shared__ u16 As[2][64*128];     // 32 KB: [0]=hi [1]=lo; XOR-16 swizzled rows
  __shared__ float sdeg[32];
  const int tid=threadIdx.x;
  const int wave=tid>>6, lane=tid&63;
  const int q=lane>>4;
  const int d0=blockIdx.x*32;
  const u32* xh32=(const u32*)xh;

  f32x4 accR[2][2], accS[2][2];
#pragma unroll
  for(int a=0;a<2;a++)
#pragma unroll
    for(int b=0;b<2;b++){ accR[a][b]=(f32x4){0.f,0.f,0.f,0.f}; accS[a][b]=(f32x4){0.f,0.f,0.f,0.f}; }

  for(int p=0;p<4;p++){
    // zero owned rows (wave owns d in [wave*8,wave*8+8), rl 0..1 -> 16 rows)
    { uint4 zz={0u,0u,0u,0u};
#pragma unroll
      for(int rl=0;rl<2;rl++)
#pragma unroll
        for(int i=0;i<2;i++){
          int row=rl*32+wave*8+i*4+(lane>>4);
          int col16=lane&15;
          *(uint4*)&As[0][row*128+col16*8]=zz;
          *(uint4*)&As[1][row*128+col16*8]=zz;
        }
    }
    // gather: wave's contiguous key range (8 dsts x 2 rels), scalar edge decode
    { u32 k0=(u32)(p*PASSB + (d0+wave*8)*2);
      u32 begW=rp[k0]+bsum[k0>>8];
      u32 k1=k0+16;
      u32 endW=rp[k1]+bsum[(k1)>>8];
      int currow=-1; float v0=0.f,v1=0.f;
      for(u32 base=begW; base<endW; base+=64){
        int nk=(int)(endW-base); if(nk>64) nk=64;
        u32 adjv=(lane<nk)?adj[base+lane]:0u;
        int i=0;
        for(; i+8<=nk; i+=8){
          u32 ww[8]; u32 hv[8];
#pragma unroll
          for(int j=0;j<8;j++){
            ww[j]=(u32)__builtin_amdgcn_readlane((int)adjv,i+j);
            hv[j]=xh32[(size_t)(ww[j]&0x7fffu)*64+lane];
          }
#pragma unroll
          for(int j=0;j<8;j++){
            int r=(int)(ww[j]>>15);
            if(r!=currow){ if(currow>=0) FLUSH2(currow); currow=r; v0=0.f; v1=0.f; }
            v0+=__uint_as_float(hv[j]<<16);
            v1+=__uint_as_float(hv[j]&0xffff0000u);
          }
        }
        for(; i<nk; i++){
          u32 w=(u32)__builtin_amdgcn_readlane((int)adjv,i);
          u32 h=xh32[(size_t)(w&0x7fffu)*64+lane];
          int r=(int)(w>>15);
          if(r!=currow){ if(currow>=0) FLUSH2(currow); currow=r; v0=0.f; v1=0.f; }
          v0+=__uint_as_float(h<<16);
          v1+=__uint_as_float(h&0xffff0000u);
        }
      }
      if(currow>=0) FLUSH2(currow);
    }
    __syncthreads();
    // GEMM relations 2p, 2p+1
#pragma unroll
    for(int rl=0;rl<2;rl++){
      const u16* Bt=Bp+(size_t)(p*2+rl)*32768;
#pragma unroll
      for(int ks=0;ks<4;ks++){
        bf16x8 ah[2],al[2];
#pragma unroll
        for(int mf=0;mf<2;mf++){
          int ar=rl*32+mf*16+(lane&15);
          int off=ar*128+((((ks<<2)+q)^(ar&15))<<3);
          ah[mf]=*(const bf16x8*)&As[0][off];
          al[mf]=*(const bf16x8*)&As[1][off];
        }
#pragma unroll
        for(int tn=0;tn<2;tn++){
          int n=wave*32+tn*16+(lane&15);
          size_t boff=((size_t)(ks*128+n))*32+q*8;
          bf16x8 bh=*(const bf16x8*)&Bt[boff];
          bf16x8 bl=*(const bf16x8*)&Bt[boff+16384];
#pragma unroll
          for(int mf=0;mf<2;mf++){
            accR[mf][tn]=__builtin_amdgcn_mfma_f32_16x16x32_bf16(ah[mf],bh,accR[mf][tn],0,0,0);
            accR[mf][tn]=__builtin_amdgcn_mfma_f32_16x16x32_bf16(al[mf],bh,accR[mf][tn],0,0,0);
            accR[mf][tn]=__builtin_amdgcn_mfma_f32_16x16x32_bf16(ah[mf],bl,accR[mf][tn],0,0,0);
          }
        }
      }
    }
    __syncthreads();
  }

  // ---- self: stage x rows d0..d0+31 hi/lo into As rows 0..31, deg into LDS ----
#pragma unroll
  for(int i=0;i<2;i++){
    int rbase=wave*8+i*4;
    int r=rbase+(lane>>4);
    int g=(lane&15)^(r&15);
    gl_lds16(xh+(size_t)(d0+r)*HD+g*8, &As[0][rbase*128]);
  }
#pragma unroll
  for(int i=0;i<2;i++){
    int rbase=wave*8+i*4;
    int r=rbase+(lane>>4);
    int g=(lane&15)^(r&15);
    gl_lds16(xl+(size_t)(d0+r)*HD+g*8, &As[1][rbase*128]);
  }
  if(tid<32){
    int g=d0+tid; u32 dg=0;
#pragma unroll
    for(int ph=0;ph<4;ph++){
      u32 k=(u32)(ph*PASSB+g*2);
      dg+=(rp[k+2]+bsum[(k+2)>>8])-(rp[k]+bsum[k>>8]);
    }
    sdeg[tid]=1.f/fmaxf((float)dg,1.f);
  }
  __syncthreads();
  { const u16* Bt=Bp+(size_t)8*32768;
#pragma unroll
    for(int ks=0;ks<4;ks++){
      bf16x8 ah[2],al[2];
#pragma unroll
      for(int mf=0;mf<2;mf++){
        int ar=mf*16+(lane&15);
        int off=ar*128+((((ks<<2)+q)^(ar&15))<<3);
        ah[mf]=*(const bf16x8*)&As[0][off];
        al[mf]=*(const bf16x8*)&As[1][off];
      }
#pragma unroll
      for(int tn=0;tn<2;tn++){
        int n=wave*32+tn*16+(lane&15);
        size_t boff=((size_t)(ks*128+n))*32+q*8;
        bf16x8 bh=*(const bf16x8*)&Bt[boff];
        bf16x8 bl=*(const bf16x8*)&Bt[boff+16384];
#pragma unroll
        for(int mf=0;mf<2;mf++){
          accS[mf][tn]=__builtin_amdgcn_mfma_f32_16x16x32_bf16(ah[mf],bh,accS[mf][tn],0,0,0);
          accS[mf][tn]=__builtin_amdgcn_mfma_f32_16x16x32_bf16(al[mf],bh,accS[mf][tn],0,0,0);
          accS[mf][tn]=__builtin_amdgcn_mfma_f32_16x16x32_bf16(ah[mf],bl,accS[mf][tn],0,0,0);
        }
      }
    }
  }

  // ---- epilogue: out = relu(accS + sb + accR/deg); C/D: col=lane&15, row=q*4+reg ----
#pragma unroll
  for(int tn=0;tn<2;tn++){
    int n=wave*32+tn*16+(lane&15);
    float bb=sb[n];
    if(last){
#pragma unroll
      for(int mf=0;mf<2;mf++)
#pragma unroll
        for(int rr=0;rr<4;rr++){
          int row=mf*16+q*4+rr;
          float v=fmaxf(accS[mf][tn][rr]+bb+accR[mf][tn][rr]*sdeg[row],0.f);
          v*=(float)mask[d0+row];
          outf[(size_t)(d0+row)*HD+n]=v;
        }
    } else {
#pragma unroll
      for(int mf=0;mf<2;mf++)
#pragma unroll
        for(int rr=0;rr<4;rr++){
          int row=mf*16+q*4+rr;
          float v=fmaxf(accS[mf][tn][rr]+bb+accR[mf][tn][rr]*sdeg[row],0.f);
          u16 hb=f2bf(v);
          u16 lb=f2bf(v-bf2f(hb));
          oh[(size_t)(d0+row)*HD+n]=hb;
          ol[(size_t)(d0+row)*HD+n]=lb;
        }
    }
  }
}

extern "C" void kernel_launch(void* const* d_in, const int* in_sizes, int n_in,
                              void* d_out, int out_size, void* d_ws, size_t ws_size,
                              hipStream_t stream)
{
  (void)in_sizes; (void)n_in; (void)out_size; (void)ws_size;
  const int*   cid =(const int*)  d_in[0];
  const int*   kid =(const int*)  d_in[1];
  const int*   mask=(const int*)  d_in[2];
  const int*   ei  =(const int*)  d_in[3];
  const int*   et  =(const int*)  d_in[4];
  const float* cemb=(const float*)d_in[5];
  const float* kemb=(const float*)d_in[6];
  const float* pW  =(const float*)d_in[7];
  const float* pb  =(const float*)d_in[8];
  const float* sW  =(const float*)d_in[9];
  const float* sb  =(const float*)d_in[10];
  const float* rW  =(const float*)d_in[11];
  float* out=(float*)d_out;
  char*  ws =(char*)d_ws;

  u16* xh =(u16*)(ws+XH_OFF);
  u16* xl =(u16*)(ws+XL_OFF);
  u16* xh2=(u16*)(ws+XH2_OFF);
  u16* xl2=(u16*)(ws+XL2_OFF);
  u32* adj =(u32*)(ws+ADJ_OFF);
  u32* rp  =(u32*)(ws+RP_OFF);
  u32* cur =(u32*)(ws+CUR_OFF);
  u32* bsum=(u32*)(ws+BSUM_OFF);
  u16* Bp  =(u16*)(ws+BP_OFF);
  const int* srcA=ei;
  const int* dstA=ei+NE;

  hipMemsetAsync(cur,0,NS*sizeof(u32),stream);
  prep_w<<<1216,256,0,stream>>>(rW,sW,pW,Bp);
  embed_mfma<<<NODES/128,256,0,stream>>>(cid,kid,cemb,kemb,Bp+PP_ELEM,pb,xh,xl);
  count_deg2<<<NE/256,256,0,stream>>>(dstA,et,cur);
  scan1<<<NS/256,256,0,stream>>>(cur,rp,bsum);
  scan2b<<<1,256,0,stream>>>(bsum,rp);
  scatter_edges2<<<NE/256,256,0,stream>>>(srcA,dstA,et,rp,bsum,cur,adj);

  fused_layer<<<NODES/32,256,0,stream>>>(xh,xl,Bp,rp,bsum,adj,sb,mask,xh2,xl2,out,0);
  fused_layer<<<NODES/32,256,0,stream>>>(xh2,xl2,Bp+BP_LAYER,rp,bsum,adj,sb+HD,mask,xh,xl,out,1);
}